// Round 1
// baseline (1153.223 us; speedup 1.0000x reference)
//
#include <hip/hip_runtime.h>

// NC=64, C=256, D=32, K=16, K_b=16, ALPHA=16, B=16, H_S=H_M=128, H_MOD=32,
// N=16384, BS=8.
#define NCC   64
#define CCH   256
#define DD    32
#define KK    16
#define KBB   16
#define AL    16
#define BRD   16
#define NTOT  16384
#define BSZ   8
#define WSROW 68

#ifndef __has_builtin
#define __has_builtin(x) 0
#endif
#if __has_builtin(__builtin_amdgcn_fdot2)
#define HAVE_FDOT2 1
#else
#define HAVE_FDOT2 0
#endif

typedef unsigned int uint32;
// NOTE: clang's amdgcn builtins use __fp16 vectors (not _Float16): cvt_pkrtz
// returns v2 __fp16 and fdot2 consumes it.
typedef __fp16 half2v __attribute__((ext_vector_type(2)));
union HU { half2v h; uint32 u; };

struct __align__(4) F4u { float a0, a1, a2, a3; };
struct __align__(4) F2u { float a, b; };
__device__ __forceinline__ F4u ld4u(const float* __restrict__ p) {
    return *reinterpret_cast<const F4u*>(p);
}
__device__ __forceinline__ float fsig(float v) { return 1.0f / (1.0f + __expf(-v)); }
__device__ __forceinline__ float ftanhf(float v) {
    return 1.0f - 2.0f / (__expf(2.0f * v) + 1.0f);
}
__device__ __forceinline__ uint32 packpair(float a, float b) {
    HU cv; cv.h = __builtin_amdgcn_cvt_pkrtz(a, b);
    return cv.u;
}
__device__ __forceinline__ void unpackpair(uint32 u, float& a, float& b) {
    HU cv; cv.u = u;
    a = (float)cv.h.x; b = (float)cv.h.y;
}
__device__ __forceinline__ float dot2(uint32 x, uint32 w, float c) {
    HU a, b; a.u = x; b.u = w;
#if HAVE_FDOT2
    return __builtin_amdgcn_fdot2(a.h, b.h, c, false);
#else
    return c + (float)a.h.x * (float)b.h.x + (float)a.h.y * (float)b.h.y;
#endif
}

// ---------------------------------------------------------------------------
// Packed shared-MLP weights (state + msg) live in device globals, written by
// kP once per launch. In kB they are indexed with wave-uniform indices so the
// compiler scalarizes the loads (s_load -> SGPR); v_dot2_f32_f16 takes one
// SGPR operand. This removes ALL LDS traffic and all barriers from kB.
// ---------------------------------------------------------------------------
__device__ __align__(16) uint32 g_w1s[128][52];
__device__ __align__(16) uint32 g_w2s[32][64];
__device__ __align__(16) float  g_b1s[128];
__device__ __align__(16) float  g_b2s[32];
__device__ __align__(16) uint32 g_w1m[128][52];
__device__ __align__(16) uint32 g_w2m[32][64];
__device__ __align__(16) float  g_b1m[128];
__device__ __align__(16) float  g_b2m[32];

__global__ __launch_bounds__(256) void kP(
    const float* __restrict__ sw1, const float* __restrict__ sb1,
    const float* __restrict__ sw2, const float* __restrict__ sb2,
    const float* __restrict__ qw1, const float* __restrict__ qb1,
    const float* __restrict__ qw2, const float* __restrict__ qb2)
{
    const int tid = blockIdx.x * 256 + threadIdx.x;
    for (int t = tid; t < 128 * 52; t += 2048) {
        const int hh = t / 52;
        const int p  = t - hh * 52;
        const int e0 = 2 * p, e1 = 2 * p + 1;
        {   // state MLP: n1 = 97
            const float f0 = (e0 < 97) ? sw1[hh * 97 + e0] : 0.0f;
            const float f1 = (e1 < 97) ? sw1[hh * 97 + e1] : 0.0f;
            g_w1s[hh][p] = packpair(f0, f1);
        }
        {   // msg MLP: n1 = 96
            const float f0 = (e0 < 96) ? qw1[hh * 96 + e0] : 0.0f;
            const float f1 = (e1 < 96) ? qw1[hh * 96 + e1] : 0.0f;
            g_w1m[hh][p] = packpair(f0, f1);
        }
    }
    for (int t = tid; t < 32 * 64; t += 2048) {
        const int d = t >> 6;
        const int p = t & 63;
        g_w2s[d][p] = packpair(sw2[d * 128 + 2 * p], sw2[d * 128 + 2 * p + 1]);
        g_w2m[d][p] = packpair(qw2[d * 128 + 2 * p], qw2[d * 128 + 2 * p + 1]);
    }
    if (tid < 128) { g_b1s[tid] = sb1[tid]; g_b1m[tid] = qb1[tid]; }
    if (tid < 32)  { g_b2s[tid] = sb2[tid]; g_b2m[tid] = qb2[tid]; }
}

// ---------------------------------------------------------------------------
// Kernel A: per-neuron mod MLP. Block = 2 neurons, 256 threads.
// v2: w1 is STAGED INTO LDS with coalesced global reads (old version streamed
// 64 scattered 452-B rows per wave-instr -> L1 thrash / HBM over-fetch).
// Rows padded 113 -> 116 floats so ds_read_b128 stays 16-B aligned.
// Thread = (nl, h|o2, bq): each thread covers 2 batches.
// ---------------------------------------------------------------------------
__global__ __launch_bounds__(256) void kA(
    const float* __restrict__ x, const float* __restrict__ h_in,
    const float* __restrict__ dlog, const float* __restrict__ prim,
    const float* __restrict__ heb, const float* __restrict__ nidp,
    const float* __restrict__ mw1, const float* __restrict__ mb1,
    const float* __restrict__ mw2, const float* __restrict__ mb2,
    float* __restrict__ outw)
{
    __shared__ __align__(16) float s_flat[2][8][116]; // [neuron][batch][113+pad]
    __shared__ __align__(16) float s_w1[64][116];     // 2 neurons x 32 rows, padded
    __shared__ __align__(16) float s_hid[2][32][8];   // [neuron][h][batch]

    const int tid = threadIdx.x;
    const int n0  = blockIdx.x * 2;
    const int nc  = n0 >> 8;
    const int c0  = n0 & 255;

    // phase 0: mod_input = [heb(16), h+inj(32), decay(1), prim(32), nid(32)]
    for (int e = tid; e < 2 * 8 * 116; e += 256) {
        const int nl = e / (8 * 116);
        const int rr = e - nl * (8 * 116);
        const int b  = rr / 116;
        const int i  = rr - b * 116;
        const int c  = c0 + nl;
        const int row = (b * NCC + nc) * CCH + c;
        float v;
        if (i < 16)        v = heb[(size_t)row * KK + i];
        else if (i < 48) { const int d = i - 16;
                           v = h_in[(size_t)row * DD + d]
                             + (c < AL ? x[(size_t)(b * NCC + nc) * DD + d] : 0.0f); }
        else if (i == 48)  v = dlog[row];
        else if (i < 81)   v = prim[(size_t)row * DD + (i - 49)];
        else if (i < 113)  v = nidp[(size_t)(nc * CCH + c) * DD + (i - 81)];
        else               v = 0.0f;
        s_flat[nl][b][i] = v;
    }
    // phase 0b: stage w1 (2 neurons, contiguous 28.9 KB) coalesced into LDS.
    {
        const float* __restrict__ gw = mw1 + (size_t)n0 * (32 * 113);
        for (int t = tid; t < 64 * 29; t += 256) {
            const int r = t / 29;           // local row 0..63
            const int c = t - r * 29;       // float4 chunk 0..28
            if (c < 28) {
                F4u v = ld4u(gw + r * 113 + c * 4);
                *(float4*)&s_w1[r][c * 4] = make_float4(v.a0, v.a1, v.a2, v.a3);
            } else {
                const float v = gw[r * 113 + 112];
                *(float4*)&s_w1[r][112] = make_float4(v, 0.0f, 0.0f, 0.0f);
            }
        }
    }
    __syncthreads();

    const int nl = tid >> 7;           // 0..1
    const int j  = (tid >> 2) & 31;    // h in phase 1, o2 in phase 2
    const int bq = tid & 3;            // batches 2bq, 2bq+1
    const int n  = n0 + nl;

    // ---- phase 1: hid[h][b] = tanh(w1[h,:] . flat[b,:] + b1[h])
    {
        const float bias = mb1[n * 32 + j];
        float acc0 = bias, acc1 = bias;
        const float* __restrict__ wr = &s_w1[nl * 32 + j][0];
        #pragma unroll
        for (int c = 0; c < 29; ++c) {
            float4 w  = *(const float4*)(wr + c * 4);
            float4 x0 = *(const float4*)&s_flat[nl][2 * bq][c * 4];
            float4 x1 = *(const float4*)&s_flat[nl][2 * bq + 1][c * 4];
            acc0 += w.x * x0.x + w.y * x0.y + w.z * x0.z + w.w * x0.w;
            acc1 += w.x * x1.x + w.y * x1.y + w.z * x1.z + w.w * x1.w;
        }
        *(float2*)&s_hid[nl][j][2 * bq] = make_float2(ftanhf(acc0), ftanhf(acc1));
    }
    __syncthreads();

    // ---- phase 2: out[b][o] = hid[b,:] . w2[:,o] + b2[o];  o = 2*j, 2*j+1
    {
        const float* __restrict__ w2base = mw2 + (size_t)n * (32 * 65);
        const float bz0 = mb2[n * 65 + 2 * j];
        const float bz1 = mb2[n * 65 + 2 * j + 1];
        float a0[2] = {bz0, bz0};
        float a1[2] = {bz1, bz1};
        #pragma unroll 4
        for (int hh = 0; hh < 32; ++hh) {
            F2u w = *(const F2u*)(w2base + hh * 65 + 2 * j);   // coalesced 8B/lane
            float2 hv = *(const float2*)&s_hid[nl][hh][2 * bq];
            a0[0] += w.a * hv.x; a0[1] += w.a * hv.y;
            a1[0] += w.b * hv.x; a1[1] += w.b * hv.y;
        }
        #pragma unroll
        for (int bb = 0; bb < 2; ++bb) {
            const int b = 2 * bq + bb;
            float* row = outw + ((size_t)b * NTOT + n) * WSROW;
            *(float2*)(row + 2 * j) = make_float2(a0[bb], a1[bb]);
        }
        if (j == 31) {  // 65th output column
            const float bz = mb2[n * 65 + 64];
            float a64[2] = {bz, bz};
            for (int hh = 0; hh < 32; ++hh) {
                const float wv = w2base[hh * 65 + 64];
                float2 hv = *(const float2*)&s_hid[nl][hh][2 * bq];
                a64[0] += wv * hv.x; a64[1] += wv * hv.y;
            }
            #pragma unroll
            for (int bb = 0; bb < 2; ++bb)
                outw[((size_t)(2 * bq + bb) * NTOT + n) * WSROW + 64] = a64[bb];
        }
    }
}

// ---------------------------------------------------------------------------
// mlp2g: xin = 52 packed half2 pairs; weights from device-global packed
// buffers with wave-uniform indices (-> scalar loads, SGPR dot2 operand).
// out[32] = layer2(tanh(layer1(xin) + b1)) + b2.
// ---------------------------------------------------------------------------
__device__ __forceinline__ void mlp2g(const uint32* xin,
                                      const uint32 (* __restrict__ w1)[52],
                                      const uint32 (* __restrict__ w2)[64],
                                      const float* __restrict__ b1,
                                      const float* __restrict__ b2, float* out)
{
    #pragma unroll
    for (int d = 0; d < 32; ++d) out[d] = b2[d];
    #pragma unroll 1
    for (int hc = 0; hc < 16; ++hc) {
        float sh[8];
        #pragma unroll
        for (int jj = 0; jj < 8; ++jj) {
            const int h = hc * 8 + jj;
            float a = b1[h];
            #pragma unroll
            for (int p = 0; p < 13; ++p) {
                uint4 wq = *(const uint4*)&w1[h][p * 4];   // uniform -> s_load_dwordx4
                a = dot2(xin[p*4+0], wq.x, a);
                a = dot2(xin[p*4+1], wq.y, a);
                a = dot2(xin[p*4+2], wq.z, a);
                a = dot2(xin[p*4+3], wq.w, a);
            }
            sh[jj] = ftanhf(a);
        }
        uint32 shp[4];
        #pragma unroll
        for (int q = 0; q < 4; ++q) shp[q] = packpair(sh[2*q], sh[2*q+1]);
        #pragma unroll
        for (int d = 0; d < 32; ++d) {
            uint4 wq = *(const uint4*)&w2[d][hc * 4];
            float a = out[d];
            a = dot2(shp[0], wq.x, a);
            a = dot2(shp[1], wq.y, a);
            a = dot2(shp[2], wq.z, a);
            a = dot2(shp[3], wq.w, a);
            out[d] = a;
        }
    }
}

// ---------------------------------------------------------------------------
// Kernel B: thread = one (b,nc,c) row. v2: no LDS, no barriers — shared MLP
// weights come from scalar loads of prepacked device globals (kP).
// ---------------------------------------------------------------------------
__global__ __launch_bounds__(256) void kB(
    const float* __restrict__ x, const float* __restrict__ h_in,
    const float* __restrict__ prev, const float* __restrict__ heb_in,
    const float* __restrict__ hebb_in,
    const float* __restrict__ nidp,
    const int* __restrict__ conn, const int* __restrict__ bconn,
    const float* __restrict__ wsm,
    float* __restrict__ o_hnew, float* __restrict__ o_msg,
    float* __restrict__ o_heb, float* __restrict__ o_hebb)
{
    const int tid = threadIdx.x;
    const int r  = blockIdx.x * 256 + tid;
    const int b  = r >> 14;
    const int n  = r & (NTOT - 1);
    const int nc = n >> 8;
    const int c  = n & 255;
    const int cellbase = (b * NCC + nc) * CCH;

    // ---- mod outputs: w_conn(16), border w(16), decay + prim -> xs[32..48]
    float ovw[16], ovb[16], decayl;
    uint32 xs[52];
    {
        const float4* op4 = (const float4*)(wsm + (size_t)r * WSROW);
        #pragma unroll
        for (int q = 0; q < 4; ++q) {
            float4 t = op4[q];
            ovw[q*4+0]=t.x; ovw[q*4+1]=t.y; ovw[q*4+2]=t.z; ovw[q*4+3]=t.w;
        }
        #pragma unroll
        for (int q = 0; q < 4; ++q) {
            float4 t = op4[4 + q];
            ovb[q*4+0]=t.x; ovb[q*4+1]=t.y; ovb[q*4+2]=t.z; ovb[q*4+3]=t.w;
        }
        float tail[36];
        #pragma unroll
        for (int q = 0; q < 9; ++q) {
            float4 t = op4[8 + q];
            tail[q*4+0]=t.x; tail[q*4+1]=t.y; tail[q*4+2]=t.z; tail[q*4+3]=t.w;
        }
        decayl = tail[0];
        #pragma unroll
        for (int q = 0; q < 16; ++q)
            xs[32 + q] = packpair(tail[1 + 2*q], tail[2 + 2*q]);   // new_prim
        xs[48] = packpair(decayl, 0.0f);
        xs[49] = xs[50] = xs[51] = 0u;
    }
    // ---- h (+ injection) -> xs[0..15]
    {
        float hvf[32];
        const float4* hp = (const float4*)(h_in + (size_t)r * DD);
        #pragma unroll
        for (int q = 0; q < 8; ++q) {
            float4 t = hp[q];
            hvf[q*4+0]=t.x; hvf[q*4+1]=t.y; hvf[q*4+2]=t.z; hvf[q*4+3]=t.w;
        }
        if (c < AL) {
            const float4* xp = (const float4*)(x + (size_t)(b * NCC + nc) * DD);
            #pragma unroll
            for (int q = 0; q < 8; ++q) {
                float4 t = xp[q];
                hvf[q*4+0]+=t.x; hvf[q*4+1]+=t.y; hvf[q*4+2]+=t.z; hvf[q*4+3]+=t.w;
            }
        }
        #pragma unroll
        for (int q = 0; q < 16; ++q) xs[q] = packpair(hvf[2*q], hvf[2*q+1]);
    }
    // ---- hebbian traces (kept for heb update)
    float hb[16];
    {
        const float4* ep = (const float4*)(heb_in + (size_t)r * KK);
        #pragma unroll
        for (int q = 0; q < 4; ++q) {
            float4 t = ep[q];
            hb[q*4+0]=t.x; hb[q*4+1]=t.y; hb[q*4+2]=t.z; hb[q*4+3]=t.w;
        }
    }
    const bool isb = (c >= AL) && (c < AL + BRD);
    // ---- aggregation -> xs[16..31]
    {
        float agg[32];
        #pragma unroll
        for (int d = 0; d < 32; ++d) agg[d] = 0.0f;
        const int4* cp = (const int4*)(conn + n * KK);
        #pragma unroll
        for (int q = 0; q < 4; ++q) {
            int4 ci = cp[q];
            int cis[4] = {ci.x, ci.y, ci.z, ci.w};
            #pragma unroll
            for (int kk = 0; kk < 4; ++kk) {
                const int k = q * 4 + kk;
                const float wk = fsig(ovw[k] + hb[k]);
                const float4* np = (const float4*)(prev + (size_t)(cellbase + cis[kk]) * DD);
                #pragma unroll
                for (int dq = 0; dq < 8; ++dq) {
                    float4 t = np[dq];
                    agg[dq*4+0] += wk*t.x; agg[dq*4+1] += wk*t.y;
                    agg[dq*4+2] += wk*t.z; agg[dq*4+3] += wk*t.w;
                }
            }
        }
        if (isb) {
            const int cb = c - AL;
            const int4*   bp  = (const int4*)(bconn + (nc * BRD + cb) * KBB);
            const float4* hp4 = (const float4*)(hebb_in + (size_t)((b * NCC + nc) * BRD + cb) * KBB);
            #pragma unroll
            for (int q = 0; q < 4; ++q) {
                int4 bi = bp[q];
                float4 hbt = hp4[q];
                int bis[4]   = {bi.x, bi.y, bi.z, bi.w};
                float hbs[4] = {hbt.x, hbt.y, hbt.z, hbt.w};
                #pragma unroll
                for (int kk = 0; kk < 4; ++kk) {
                    const int k   = q * 4 + kk;
                    const int idx = bis[kk];
                    const int nb  = idx >> 4;
                    const int ch  = AL + (idx & 15);
                    const float wk = fsig(ovb[k] + hbs[kk]);
                    const float4* np = (const float4*)(prev + (size_t)((b * NCC + nb) * CCH + ch) * DD);
                    #pragma unroll
                    for (int dq = 0; dq < 8; ++dq) {
                        float4 t = np[dq];
                        agg[dq*4+0] += wk*t.x; agg[dq*4+1] += wk*t.y;
                        agg[dq*4+2] += wk*t.z; agg[dq*4+3] += wk*t.w;
                    }
                }
            }
        }
        #pragma unroll
        for (int q = 0; q < 16; ++q) xs[16 + q] = packpair(agg[2*q], agg[2*q+1]);
    }

    // ---- state MLP + h_new
    uint32 hnp[16];
    {
        float delta[32];
        mlp2g(xs, g_w1s, g_w2s, g_b1s, g_b2s, delta);
        const float sd = fsig(decayl);
        float* hrow = o_hnew + (size_t)r * DD;
        #pragma unroll
        for (int q = 0; q < 16; ++q) {
            float h0, h1;
            unpackpair(xs[q], h0, h1);
            const float t0 = sd * h0 + (1.0f - sd) * ftanhf(delta[2*q]);
            const float t1 = sd * h1 + (1.0f - sd) * ftanhf(delta[2*q+1]);
            hnp[q] = packpair(t0, t1);
            *(float2*)(hrow + 2*q) = make_float2(t0, t1);
        }
    }

    // ---- msg MLP: [h_new(32), agg(32), nid(32)]
    float macc[32];
    {
        uint32 xm[52];
        #pragma unroll
        for (int q = 0; q < 16; ++q) xm[q] = hnp[q];
        #pragma unroll
        for (int q = 0; q < 16; ++q) xm[16 + q] = xs[16 + q];
        const float4* npd = (const float4*)(nidp + (size_t)n * DD);
        #pragma unroll
        for (int q = 0; q < 8; ++q) {
            float4 t = npd[q];
            xm[32 + 2*q]     = packpair(t.x, t.y);
            xm[32 + 2*q + 1] = packpair(t.z, t.w);
        }
        xm[48] = xm[49] = xm[50] = xm[51] = 0u;
        mlp2g(xm, g_w1m, g_w2m, g_b1m, g_b2m, macc);
        float4* mop = (float4*)(o_msg + (size_t)r * DD);
        #pragma unroll
        for (int q = 0; q < 8; ++q)
            mop[q] = make_float4(macc[q*4+0], macc[q*4+1], macc[q*4+2], macc[q*4+3]);
    }

    // ---- hebbian updates
    {
        const int4* cp = (const int4*)(conn + n * KK);
        #pragma unroll
        for (int q = 0; q < 4; ++q) {
            int4 ci = cp[q];
            int cis[4] = {ci.x, ci.y, ci.z, ci.w};
            float hres[4];
            #pragma unroll
            for (int kk = 0; kk < 4; ++kk) {
                const float4* np = (const float4*)(prev + (size_t)(cellbase + cis[kk]) * DD);
                float dot = 0.0f;
                #pragma unroll
                for (int dq = 0; dq < 8; ++dq) {
                    float4 t = np[dq];
                    dot += macc[dq*4+0]*t.x + macc[dq*4+1]*t.y
                         + macc[dq*4+2]*t.z + macc[dq*4+3]*t.w;
                }
                hres[kk] = 0.9f * hb[q*4+kk] + 0.003125f * dot;
            }
            *(float4*)(o_heb + (size_t)r * KK + q*4)
                = make_float4(hres[0], hres[1], hres[2], hres[3]);
        }
    }
    if (isb) {
        const int cb = c - AL;
        const int4*   bp  = (const int4*)(bconn + (nc * BRD + cb) * KBB);
        const float4* hp4 = (const float4*)(hebb_in + (size_t)((b * NCC + nc) * BRD + cb) * KBB);
        #pragma unroll
        for (int q = 0; q < 4; ++q) {
            int4 bi = bp[q];
            float4 hbt = hp4[q];
            int bis[4]   = {bi.x, bi.y, bi.z, bi.w};
            float hbs[4] = {hbt.x, hbt.y, hbt.z, hbt.w};
            float hres[4];
            #pragma unroll
            for (int kk = 0; kk < 4; ++kk) {
                const int idx = bis[kk];
                const int nb  = idx >> 4;
                const int ch  = AL + (idx & 15);
                const float4* np = (const float4*)(prev + (size_t)((b * NCC + nb) * CCH + ch) * DD);
                float dot = 0.0f;
                #pragma unroll
                for (int dq = 0; dq < 8; ++dq) {
                    float4 t = np[dq];
                    dot += macc[dq*4+0]*t.x + macc[dq*4+1]*t.y
                         + macc[dq*4+2]*t.z + macc[dq*4+3]*t.w;
                }
                hres[kk] = 0.9f * hbs[kk] + 0.003125f * dot;
            }
            *(float4*)(o_hebb + (size_t)((b * NCC + nc) * BRD + cb) * KBB + q*4)
                = make_float4(hres[0], hres[1], hres[2], hres[3]);
        }
    }
}

// ---------------------------------------------------------------------------
// Kernel C: readout = mean over channels [C-ALPHA, C) of msg -> (BS, NC*D)
// ---------------------------------------------------------------------------
__global__ __launch_bounds__(256) void kC(const float* __restrict__ msg,
                                          float* __restrict__ ro)
{
    const int t = blockIdx.x * 256 + threadIdx.x;
    const int b   = t >> 11;
    const int rem = t & 2047;
    const int nc  = rem >> 5;
    const int d   = rem & 31;
    const float* mp = msg + (size_t)((b * NCC + nc) * CCH + (CCH - AL)) * DD + d;
    float s = 0.0f;
    #pragma unroll
    for (int j = 0; j < 16; ++j) s += mp[j * DD];
    ro[t] = s * (1.0f / 16.0f);
}

extern "C" void kernel_launch(void* const* d_in, const int* in_sizes, int n_in,
                              void* d_out, int out_size, void* d_ws, size_t ws_size,
                              hipStream_t stream) {
    const float* x     = (const float*)d_in[0];
    const float* h     = (const float*)d_in[1];
    const float* prev  = (const float*)d_in[2];
    const float* dlog  = (const float*)d_in[3];
    const float* prim  = (const float*)d_in[4];
    const float* heb   = (const float*)d_in[5];
    const float* hebb  = (const float*)d_in[6];
    const float* sw1   = (const float*)d_in[7];
    const float* sb1   = (const float*)d_in[8];
    const float* sw2   = (const float*)d_in[9];
    const float* sb2   = (const float*)d_in[10];
    const float* qw1   = (const float*)d_in[11];
    const float* qb1   = (const float*)d_in[12];
    const float* qw2   = (const float*)d_in[13];
    const float* qb2   = (const float*)d_in[14];
    const float* mw1   = (const float*)d_in[15];
    const float* mb1   = (const float*)d_in[16];
    const float* mw2   = (const float*)d_in[17];
    const float* mb2   = (const float*)d_in[18];
    const float* nid   = (const float*)d_in[19];
    const int*   conn  = (const int*)d_in[20];
    const int*   bconn = (const int*)d_in[21];

    float* out   = (float*)d_out;
    float* ro    = out;                          // (8, 2048)
    float* hnew  = out + 16384;                  // (8,64,256,32)
    float* msg   = hnew + 4194304;               // (8,64,256,32)
    float* hebo  = msg + 4194304;                // (8,64,256,16)
    float* hebbo = hebo + 2097152;               // (8,64,16,16)
    float* ws    = (float*)d_ws;                 // 8*16384*68*4 = 35,651,584 B

    kP<<<8, 256, 0, stream>>>(sw1, sb1, sw2, sb2, qw1, qb1, qw2, qb2);
    kA<<<NTOT / 2, 256, 0, stream>>>(x, h, dlog, prim, heb, nid, mw1, mb1, mw2, mb2, ws);
    kB<<<(BSZ * NTOT) / 256, 256, 0, stream>>>(x, h, prev, heb, hebb,
                                               nid, conn, bconn, ws,
                                               hnew, msg, hebo, hebbo);
    kC<<<64, 256, 0, stream>>>(msg, ro);
}

// Round 2
// 993.612 us; speedup vs baseline: 1.1606x; 1.1606x over previous
//
#include <hip/hip_runtime.h>

// NC=64, C=256, D=32, K=16, K_b=16, ALPHA=16, B=16, H_S=H_M=128, H_MOD=32,
// N=16384, BS=8.
#define NCC   64
#define CCH   256
#define DD    32
#define KK    16
#define KBB   16
#define AL    16
#define BRD   16
#define NTOT  16384
#define BSZ   8
#define WSROW 68

#ifndef __has_builtin
#define __has_builtin(x) 0
#endif
#if __has_builtin(__builtin_amdgcn_fdot2)
#define HAVE_FDOT2 1
#else
#define HAVE_FDOT2 0
#endif

typedef unsigned int uint32;
// NOTE: clang's amdgcn builtins use __fp16 vectors (not _Float16): cvt_pkrtz
// returns v2 __fp16 and fdot2 consumes it.
typedef __fp16 half2v __attribute__((ext_vector_type(2)));
union HU { half2v h; uint32 u; };

struct __align__(4) F4u { float a0, a1, a2, a3; };
struct __align__(4) F2u { float a, b; };
__device__ __forceinline__ F4u ld4u(const float* __restrict__ p) {
    return *reinterpret_cast<const F4u*>(p);
}
__device__ __forceinline__ float fsig(float v) { return 1.0f / (1.0f + __expf(-v)); }
__device__ __forceinline__ float ftanhf(float v) {
    return 1.0f - 2.0f / (__expf(2.0f * v) + 1.0f);
}
__device__ __forceinline__ uint32 packpair(float a, float b) {
    HU cv; cv.h = __builtin_amdgcn_cvt_pkrtz(a, b);
    return cv.u;
}
__device__ __forceinline__ void unpackpair(uint32 u, float& a, float& b) {
    HU cv; cv.u = u;
    a = (float)cv.h.x; b = (float)cv.h.y;
}
__device__ __forceinline__ float dot2(uint32 x, uint32 w, float c) {
    HU a, b; a.u = x; b.u = w;
#if HAVE_FDOT2
    return __builtin_amdgcn_fdot2(a.h, b.h, c, false);
#else
    return c + (float)a.h.x * (float)b.h.x + (float)a.h.y * (float)b.h.y;
#endif
}

// ---------------------------------------------------------------------------
// Kernel A1: layer 1 of the per-neuron mod MLP. One block = ONE neuron.
// 3.7 KB LDS (input vector only), one barrier, thread=(h,b) streams its own
// w1 row from global with f32 FMA. Per-wave w1 working set = 8 rows x 452 B
// (L1-resident, each HBM line consumed fully). hid -> scratch (msg region,
// overwritten by kB later): hid[n][h][b], 256 contiguous floats per block.
// ---------------------------------------------------------------------------
__global__ __launch_bounds__(256) void kA1(
    const float* __restrict__ x, const float* __restrict__ h_in,
    const float* __restrict__ dlog, const float* __restrict__ prim,
    const float* __restrict__ heb, const float* __restrict__ nidp,
    const float* __restrict__ mw1, const float* __restrict__ mb1,
    float* __restrict__ hidout)
{
    __shared__ __align__(16) float s_flat[8][116];   // [batch][113+pad]

    const int tid = threadIdx.x;
    const int n   = blockIdx.x;
    const int nc  = n >> 8;
    const int c   = n & 255;

    // assemble mod_input = [heb(16), h+inj(32), decay(1), prim(32), nid(32)]
    for (int e = tid; e < 8 * 116; e += 256) {
        const int b = e / 116;
        const int i = e - b * 116;
        const int row = (b * NCC + nc) * CCH + c;
        float v;
        if (i < 16)        v = heb[(size_t)row * KK + i];
        else if (i < 48) { const int d = i - 16;
                           v = h_in[(size_t)row * DD + d]
                             + (c < AL ? x[(size_t)(b * NCC + nc) * DD + d] : 0.0f); }
        else if (i == 48)  v = dlog[row];
        else if (i < 81)   v = prim[(size_t)row * DD + (i - 49)];
        else if (i < 113)  v = nidp[(size_t)(nc * CCH + c) * DD + (i - 81)];
        else               v = 0.0f;
        s_flat[b][i] = v;
    }
    __syncthreads();

    const int h = tid >> 3;       // 0..31
    const int b = tid & 7;        // 0..7
    const float* __restrict__ wr = mw1 + ((size_t)n * 32 + h) * 113;
    float acc = mb1[n * 32 + h];
    #pragma unroll
    for (int cq = 0; cq < 28; ++cq) {
        F4u w = ld4u(wr + cq * 4);                       // row stride 452B: 8 rows/wave, L1-hot
        float4 xv = *(const float4*)&s_flat[b][cq * 4];  // 8 distinct addrs, distinct banks
        acc += w.a0 * xv.x + w.a1 * xv.y + w.a2 * xv.z + w.a3 * xv.w;
    }
    acc += wr[112] * s_flat[b][112];
    hidout[(size_t)n * 256 + tid] = ftanhf(acc);         // perfectly coalesced
}

// ---------------------------------------------------------------------------
// Kernel A2: layer 2. One block = ONE neuron. Stage the neuron's contiguous
// 8.3 KB w2 + 1 KB hid into LDS (coalesced), one barrier, then 520 dots of
// length 32 from LDS broadcast. Writes the 65-wide ws rows.
// ---------------------------------------------------------------------------
__global__ __launch_bounds__(256) void kA2(
    const float* __restrict__ hidin,
    const float* __restrict__ mw2, const float* __restrict__ mb2,
    float* __restrict__ outw)
{
    __shared__ __align__(16) float s_w2[32 * 65];   // 2080 floats
    __shared__ __align__(16) float s_h2[256];       // hid[h][b]

    const int tid = threadIdx.x;
    const int n   = blockIdx.x;

    {
        const float4* src = (const float4*)(mw2 + (size_t)n * (32 * 65));
        float4* dst = (float4*)s_w2;
        for (int u = tid; u < 520; u += 256) dst[u] = src[u];
        if (tid < 64)
            ((float4*)s_h2)[tid] = ((const float4*)(hidin + (size_t)n * 256))[tid];
    }
    __syncthreads();

    for (int it = tid; it < 520; it += 256) {
        const int o = it >> 3;     // 0..64
        const int b = it & 7;
        float acc = mb2[n * 65 + o];
        #pragma unroll 8
        for (int hh = 0; hh < 32; ++hh)
            acc += s_w2[hh * 65 + o] * s_h2[hh * 8 + b];
        outw[((size_t)b * NTOT + n) * WSROW + o] = acc;
    }
}

// ---------------------------------------------------------------------------
// Kernel B helpers: stage one MLP's weights into LDS as packed f16 pairs.
// w1buf[h][p] = input pair (2p,2p+1) of the zero-padded-104 input vector;
// w2buf[d][p] = hidden pair (2p,2p+1) over the 128 hiddens.
// (Round-1 lesson: same-address ds_read broadcasts are free; the s_load/SGPR
// variant was SLOWER — keep the LDS form.)
// ---------------------------------------------------------------------------
__device__ __forceinline__ void stageW(int tid, const float* __restrict__ w1g, int n1,
                                       const float* __restrict__ b1g,
                                       const float* __restrict__ w2g,
                                       const float* __restrict__ b2g,
                                       uint32 (*w1buf)[52], uint32 (*w2buf)[64],
                                       float* b1buf, float* b2buf)
{
    for (int t = tid; t < 128 * 52; t += 256) {
        const int hh = t / 52;
        const int p  = t - hh * 52;
        const int e0 = 2 * p, e1 = 2 * p + 1;
        const float f0 = (e0 < n1) ? w1g[hh * n1 + e0] : 0.0f;
        const float f1 = (e1 < n1) ? w1g[hh * n1 + e1] : 0.0f;
        w1buf[hh][p] = packpair(f0, f1);
    }
    for (int t = tid; t < 32 * 64; t += 256) {
        const int d = t >> 6;
        const int p = t & 63;
        w2buf[d][p] = packpair(w2g[d * 128 + 2 * p], w2g[d * 128 + 2 * p + 1]);
    }
    if (tid < 128) b1buf[tid] = b1g[tid];
    if (tid < 32)  b2buf[tid] = b2g[tid];
}

// xin: 52 packed half2 pairs. out[32] = layer2(tanh(layer1(xin) + b1)) + b2.
__device__ __forceinline__ void mlp2(const uint32* xin,
                                     const uint32 (*w1)[52], const uint32 (*w2)[64],
                                     const float* b1, const float* b2, float* out)
{
    #pragma unroll
    for (int d = 0; d < 32; ++d) out[d] = b2[d];
    #pragma unroll 1
    for (int hc = 0; hc < 16; ++hc) {
        float sh[8];
        #pragma unroll
        for (int jj = 0; jj < 8; ++jj) {
            const int h = hc * 8 + jj;
            float a = b1[h];
            #pragma unroll
            for (int p = 0; p < 13; ++p) {
                uint4 wq = *(const uint4*)&w1[h][p * 4];   // ds_read_b128 broadcast
                a = dot2(xin[p*4+0], wq.x, a);
                a = dot2(xin[p*4+1], wq.y, a);
                a = dot2(xin[p*4+2], wq.z, a);
                a = dot2(xin[p*4+3], wq.w, a);
            }
            sh[jj] = ftanhf(a);
        }
        uint32 shp[4];
        #pragma unroll
        for (int q = 0; q < 4; ++q) shp[q] = packpair(sh[2*q], sh[2*q+1]);
        #pragma unroll
        for (int d = 0; d < 32; ++d) {
            uint4 wq = *(const uint4*)&w2[d][hc * 4];
            float a = out[d];
            a = dot2(shp[0], wq.x, a);
            a = dot2(shp[1], wq.y, a);
            a = dot2(shp[2], wq.z, a);
            a = dot2(shp[3], wq.w, a);
            out[d] = a;
        }
    }
}

// ---------------------------------------------------------------------------
// Kernel B: thread = one (b,nc,c) row. Shared MLP weights live in LDS as f16,
// consumed with v_dot2_f32_f16 (f32 accumulate). Two staging phases:
// state weights, then msg weights. (Round-0 proven form.)
// ---------------------------------------------------------------------------
__global__ __launch_bounds__(256) void kB(
    const float* __restrict__ x, const float* __restrict__ h_in,
    const float* __restrict__ prev, const float* __restrict__ heb_in,
    const float* __restrict__ hebb_in,
    const float* __restrict__ sw1, const float* __restrict__ sb1,
    const float* __restrict__ sw2, const float* __restrict__ sb2,
    const float* __restrict__ qw1, const float* __restrict__ qb1,
    const float* __restrict__ qw2, const float* __restrict__ qb2,
    const float* __restrict__ nidp,
    const int* __restrict__ conn, const int* __restrict__ bconn,
    const float* __restrict__ wsm,
    float* __restrict__ o_hnew, float* __restrict__ o_msg,
    float* __restrict__ o_heb, float* __restrict__ o_hebb)
{
    __shared__ __align__(16) uint32 w1buf[128][52];
    __shared__ __align__(16) uint32 w2buf[32][64];
    __shared__ float b1buf[128];
    __shared__ float b2buf[32];

    const int tid = threadIdx.x;
    const int r  = blockIdx.x * 256 + tid;
    const int b  = r >> 14;
    const int n  = r & (NTOT - 1);
    const int nc = n >> 8;
    const int c  = n & 255;
    const int cellbase = (b * NCC + nc) * CCH;

    stageW(tid, sw1, 97, sb1, sw2, sb2, w1buf, w2buf, b1buf, b2buf);
    __syncthreads();

    // ---- mod outputs: w_conn(16), border w(16), decay + prim -> xs[32..48]
    float ovw[16], ovb[16], decayl;
    uint32 xs[52];
    {
        const float4* op4 = (const float4*)(wsm + (size_t)r * WSROW);
        #pragma unroll
        for (int q = 0; q < 4; ++q) {
            float4 t = op4[q];
            ovw[q*4+0]=t.x; ovw[q*4+1]=t.y; ovw[q*4+2]=t.z; ovw[q*4+3]=t.w;
        }
        #pragma unroll
        for (int q = 0; q < 4; ++q) {
            float4 t = op4[4 + q];
            ovb[q*4+0]=t.x; ovb[q*4+1]=t.y; ovb[q*4+2]=t.z; ovb[q*4+3]=t.w;
        }
        float tail[36];
        #pragma unroll
        for (int q = 0; q < 9; ++q) {
            float4 t = op4[8 + q];
            tail[q*4+0]=t.x; tail[q*4+1]=t.y; tail[q*4+2]=t.z; tail[q*4+3]=t.w;
        }
        decayl = tail[0];
        #pragma unroll
        for (int q = 0; q < 16; ++q)
            xs[32 + q] = packpair(tail[1 + 2*q], tail[2 + 2*q]);   // new_prim
        xs[48] = packpair(decayl, 0.0f);
        xs[49] = xs[50] = xs[51] = 0u;
    }
    // ---- h (+ injection) -> xs[0..15]
    {
        float hvf[32];
        const float4* hp = (const float4*)(h_in + (size_t)r * DD);
        #pragma unroll
        for (int q = 0; q < 8; ++q) {
            float4 t = hp[q];
            hvf[q*4+0]=t.x; hvf[q*4+1]=t.y; hvf[q*4+2]=t.z; hvf[q*4+3]=t.w;
        }
        if (c < AL) {
            const float4* xp = (const float4*)(x + (size_t)(b * NCC + nc) * DD);
            #pragma unroll
            for (int q = 0; q < 8; ++q) {
                float4 t = xp[q];
                hvf[q*4+0]+=t.x; hvf[q*4+1]+=t.y; hvf[q*4+2]+=t.z; hvf[q*4+3]+=t.w;
            }
        }
        #pragma unroll
        for (int q = 0; q < 16; ++q) xs[q] = packpair(hvf[2*q], hvf[2*q+1]);
    }
    // ---- hebbian traces (kept for heb update)
    float hb[16];
    {
        const float4* ep = (const float4*)(heb_in + (size_t)r * KK);
        #pragma unroll
        for (int q = 0; q < 4; ++q) {
            float4 t = ep[q];
            hb[q*4+0]=t.x; hb[q*4+1]=t.y; hb[q*4+2]=t.z; hb[q*4+3]=t.w;
        }
    }
    const bool isb = (c >= AL) && (c < AL + BRD);
    // ---- aggregation -> xs[16..31]
    {
        float agg[32];
        #pragma unroll
        for (int d = 0; d < 32; ++d) agg[d] = 0.0f;
        const int4* cp = (const int4*)(conn + n * KK);
        #pragma unroll
        for (int q = 0; q < 4; ++q) {
            int4 ci = cp[q];
            int cis[4] = {ci.x, ci.y, ci.z, ci.w};
            #pragma unroll
            for (int kk = 0; kk < 4; ++kk) {
                const int k = q * 4 + kk;
                const float wk = fsig(ovw[k] + hb[k]);
                const float4* np = (const float4*)(prev + (size_t)(cellbase + cis[kk]) * DD);
                #pragma unroll
                for (int dq = 0; dq < 8; ++dq) {
                    float4 t = np[dq];
                    agg[dq*4+0] += wk*t.x; agg[dq*4+1] += wk*t.y;
                    agg[dq*4+2] += wk*t.z; agg[dq*4+3] += wk*t.w;
                }
            }
        }
        if (isb) {
            const int cb = c - AL;
            const int4*   bp  = (const int4*)(bconn + (nc * BRD + cb) * KBB);
            const float4* hp4 = (const float4*)(hebb_in + (size_t)((b * NCC + nc) * BRD + cb) * KBB);
            #pragma unroll
            for (int q = 0; q < 4; ++q) {
                int4 bi = bp[q];
                float4 hbt = hp4[q];
                int bis[4]   = {bi.x, bi.y, bi.z, bi.w};
                float hbs[4] = {hbt.x, hbt.y, hbt.z, hbt.w};
                #pragma unroll
                for (int kk = 0; kk < 4; ++kk) {
                    const int k   = q * 4 + kk;
                    const int idx = bis[kk];
                    const int nb  = idx >> 4;
                    const int ch  = AL + (idx & 15);
                    const float wk = fsig(ovb[k] + hbs[kk]);
                    const float4* np = (const float4*)(prev + (size_t)((b * NCC + nb) * CCH + ch) * DD);
                    #pragma unroll
                    for (int dq = 0; dq < 8; ++dq) {
                        float4 t = np[dq];
                        agg[dq*4+0] += wk*t.x; agg[dq*4+1] += wk*t.y;
                        agg[dq*4+2] += wk*t.z; agg[dq*4+3] += wk*t.w;
                    }
                }
            }
        }
        #pragma unroll
        for (int q = 0; q < 16; ++q) xs[16 + q] = packpair(agg[2*q], agg[2*q+1]);
    }

    // ---- state MLP + h_new
    uint32 hnp[16];
    {
        float delta[32];
        mlp2(xs, w1buf, w2buf, b1buf, b2buf, delta);
        const float sd = fsig(decayl);
        float* hrow = o_hnew + (size_t)r * DD;
        #pragma unroll
        for (int q = 0; q < 16; ++q) {
            float h0, h1;
            unpackpair(xs[q], h0, h1);
            const float t0 = sd * h0 + (1.0f - sd) * ftanhf(delta[2*q]);
            const float t1 = sd * h1 + (1.0f - sd) * ftanhf(delta[2*q+1]);
            hnp[q] = packpair(t0, t1);
            *(float2*)(hrow + 2*q) = make_float2(t0, t1);
        }
    }

    __syncthreads();
    stageW(tid, qw1, 96, qb1, qw2, qb2, w1buf, w2buf, b1buf, b2buf);
    __syncthreads();

    // ---- msg MLP: [h_new(32), agg(32), nid(32)]
    float macc[32];
    {
        uint32 xm[52];
        #pragma unroll
        for (int q = 0; q < 16; ++q) xm[q] = hnp[q];
        #pragma unroll
        for (int q = 0; q < 16; ++q) xm[16 + q] = xs[16 + q];
        const float4* npd = (const float4*)(nidp + (size_t)n * DD);
        #pragma unroll
        for (int q = 0; q < 8; ++q) {
            float4 t = npd[q];
            xm[32 + 2*q]     = packpair(t.x, t.y);
            xm[32 + 2*q + 1] = packpair(t.z, t.w);
        }
        xm[48] = xm[49] = xm[50] = xm[51] = 0u;
        mlp2(xm, w1buf, w2buf, b1buf, b2buf, macc);
        float4* mop = (float4*)(o_msg + (size_t)r * DD);
        #pragma unroll
        for (int q = 0; q < 8; ++q)
            mop[q] = make_float4(macc[q*4+0], macc[q*4+1], macc[q*4+2], macc[q*4+3]);
    }

    // ---- hebbian updates
    {
        const int4* cp = (const int4*)(conn + n * KK);
        #pragma unroll
        for (int q = 0; q < 4; ++q) {
            int4 ci = cp[q];
            int cis[4] = {ci.x, ci.y, ci.z, ci.w};
            float hres[4];
            #pragma unroll
            for (int kk = 0; kk < 4; ++kk) {
                const float4* np = (const float4*)(prev + (size_t)(cellbase + cis[kk]) * DD);
                float dot = 0.0f;
                #pragma unroll
                for (int dq = 0; dq < 8; ++dq) {
                    float4 t = np[dq];
                    dot += macc[dq*4+0]*t.x + macc[dq*4+1]*t.y
                         + macc[dq*4+2]*t.z + macc[dq*4+3]*t.w;
                }
                hres[kk] = 0.9f * hb[q*4+kk] + 0.003125f * dot;
            }
            *(float4*)(o_heb + (size_t)r * KK + q*4)
                = make_float4(hres[0], hres[1], hres[2], hres[3]);
        }
    }
    if (isb) {
        const int cb = c - AL;
        const int4*   bp  = (const int4*)(bconn + (nc * BRD + cb) * KBB);
        const float4* hp4 = (const float4*)(hebb_in + (size_t)((b * NCC + nc) * BRD + cb) * KBB);
        #pragma unroll
        for (int q = 0; q < 4; ++q) {
            int4 bi = bp[q];
            float4 hbt = hp4[q];
            int bis[4]   = {bi.x, bi.y, bi.z, bi.w};
            float hbs[4] = {hbt.x, hbt.y, hbt.z, hbt.w};
            float hres[4];
            #pragma unroll
            for (int kk = 0; kk < 4; ++kk) {
                const int idx = bis[kk];
                const int nb  = idx >> 4;
                const int ch  = AL + (idx & 15);
                const float4* np = (const float4*)(prev + (size_t)((b * NCC + nb) * CCH + ch) * DD);
                float dot = 0.0f;
                #pragma unroll
                for (int dq = 0; dq < 8; ++dq) {
                    float4 t = np[dq];
                    dot += macc[dq*4+0]*t.x + macc[dq*4+1]*t.y
                         + macc[dq*4+2]*t.z + macc[dq*4+3]*t.w;
                }
                hres[kk] = 0.9f * hbs[kk] + 0.003125f * dot;
            }
            *(float4*)(o_hebb + (size_t)((b * NCC + nc) * BRD + cb) * KBB + q*4)
                = make_float4(hres[0], hres[1], hres[2], hres[3]);
        }
    }
}

// ---------------------------------------------------------------------------
// Kernel C: readout = mean over channels [C-ALPHA, C) of msg -> (BS, NC*D)
// ---------------------------------------------------------------------------
__global__ __launch_bounds__(256) void kC(const float* __restrict__ msg,
                                          float* __restrict__ ro)
{
    const int t = blockIdx.x * 256 + threadIdx.x;
    const int b   = t >> 11;
    const int rem = t & 2047;
    const int nc  = rem >> 5;
    const int d   = rem & 31;
    const float* mp = msg + (size_t)((b * NCC + nc) * CCH + (CCH - AL)) * DD + d;
    float s = 0.0f;
    #pragma unroll
    for (int j = 0; j < 16; ++j) s += mp[j * DD];
    ro[t] = s * (1.0f / 16.0f);
}

extern "C" void kernel_launch(void* const* d_in, const int* in_sizes, int n_in,
                              void* d_out, int out_size, void* d_ws, size_t ws_size,
                              hipStream_t stream) {
    const float* x     = (const float*)d_in[0];
    const float* h     = (const float*)d_in[1];
    const float* prev  = (const float*)d_in[2];
    const float* dlog  = (const float*)d_in[3];
    const float* prim  = (const float*)d_in[4];
    const float* heb   = (const float*)d_in[5];
    const float* hebb  = (const float*)d_in[6];
    const float* sw1   = (const float*)d_in[7];
    const float* sb1   = (const float*)d_in[8];
    const float* sw2   = (const float*)d_in[9];
    const float* sb2   = (const float*)d_in[10];
    const float* qw1   = (const float*)d_in[11];
    const float* qb1   = (const float*)d_in[12];
    const float* qw2   = (const float*)d_in[13];
    const float* qb2   = (const float*)d_in[14];
    const float* mw1   = (const float*)d_in[15];
    const float* mb1   = (const float*)d_in[16];
    const float* mw2   = (const float*)d_in[17];
    const float* mb2   = (const float*)d_in[18];
    const float* nid   = (const float*)d_in[19];
    const int*   conn  = (const int*)d_in[20];
    const int*   bconn = (const int*)d_in[21];

    float* out   = (float*)d_out;
    float* ro    = out;                          // (8, 2048)
    float* hnew  = out + 16384;                  // (8,64,256,32)
    float* msg   = hnew + 4194304;               // (8,64,256,32)
    float* hebo  = msg + 4194304;                // (8,64,256,16)
    float* hebbo = hebo + 2097152;               // (8,64,16,16)
    float* ws    = (float*)d_ws;                 // 8*16384*68*4 = 35,651,584 B

    // hid scratch (16384*256 floats = msg region size exactly); kB overwrites
    // msg afterwards, so this aliasing is safe.
    float* hidscratch = msg;

    kA1<<<NTOT, 256, 0, stream>>>(x, h, dlog, prim, heb, nid, mw1, mb1, hidscratch);
    kA2<<<NTOT, 256, 0, stream>>>(hidscratch, mw2, mb2, ws);
    kB<<<(BSZ * NTOT) / 256, 256, 0, stream>>>(x, h, prev, heb, hebb,
                                               sw1, sb1, sw2, sb2,
                                               qw1, qb1, qw2, qb2,
                                               nid, conn, bconn, ws,
                                               hnew, msg, hebo, hebbo);
    kC<<<64, 256, 0, stream>>>(msg, ro);
}